// Round 2
// baseline (281.706 us; speedup 1.0000x reference)
//
#include <hip/hip_runtime.h>
#include <hip/hip_bf16.h>

#define B_ROWS 65536
#define NA 128
#define D_OUT 1024
#define VBS 128
#define NCHUNK (B_ROWS / VBS)   // 512

typedef __attribute__((ext_vector_type(8))) short bf16x8s;
typedef __attribute__((ext_vector_type(4))) float f32x4;
typedef __attribute__((ext_vector_type(4))) unsigned short u16x4;
typedef __attribute__((ext_vector_type(8))) unsigned short u16x8;

static __device__ __forceinline__ short f2bf(float f) {
    unsigned u = __builtin_bit_cast(unsigned, f);
    u = u + 0x7FFFu + ((u >> 16) & 1u);   // round-to-nearest-even to bf16
    return (short)(u >> 16);
}
static __device__ __forceinline__ float bf2f(unsigned short h) {
    unsigned u = ((unsigned)h) << 16;
    return __builtin_bit_cast(float, u);
}

// One block per virtual batch (chunk): 128 threads, one per feature.
__global__ void gbn_stats_kernel(const float* __restrict__ a,
                                 const float* __restrict__ gamma,
                                 const float* __restrict__ beta,
                                 float* __restrict__ ss) {
    int c = blockIdx.x;
    int j = threadIdx.x;            // feature 0..127
    const float* p = a + (size_t)c * (VBS * NA) + j;
    float s = 0.f, s2 = 0.f;
#pragma unroll 8
    for (int r = 0; r < VBS; ++r) {
        float v = p[r * NA];
        s += v; s2 += v * v;
    }
    float mean = s * (1.f / VBS);
    float var  = fmaxf(s2 * (1.f / VBS) - mean * mean, 0.f);   // biased var
    float sc = gamma[j] * rsqrtf(var + 1e-5f);
    float sh = beta[j] - mean * sc;
    float2* o = (float2*)ss + (c * NA + j);
    *o = make_float2(sc, sh);
}

__global__ void wcast_kernel(const float* __restrict__ W,
                             unsigned short* __restrict__ Wb, int n) {
    int i = blockIdx.x * blockDim.x + threadIdx.x;
    if (i < n) Wb[i] = (unsigned short)f2bf(W[i]);
}

// One block per 16 output rows. 256 threads = 4 waves; wave w owns cols [w*256, w*256+256).
// Swapped-operand MFMA: thread (g,q) holds y[r0+q][w*256 + nf*16 + 4g + r] -> float4-
// contiguous columns per thread. Epilogue: *prior (float4), bf16 LDS transpose, then
// per-row Michelot sparsemax in registers (no barriers in loop), vectorized out.
__global__ __launch_bounds__(256, 4) void fused_kernel(
    const float* __restrict__ a,
    const float* __restrict__ prior,
    const float* __restrict__ ss,
    const unsigned short* __restrict__ Wb,
    float* __restrict__ out) {

    const int tid  = threadIdx.x;
    const int wave = tid >> 6;        // 0..3  (N block of 256)
    const int lane = tid & 63;
    const int g    = lane >> 4;       // 0..3
    const int q    = lane & 15;       // row within tile / A(i)=W-row, B(j)=a-row

    const int r0    = blockIdx.x * 16;
    const int chunk = r0 >> 7;

    f32x4 acc[16];
#pragma unroll
    for (int i = 0; i < 16; ++i) acc[i] = (f32x4){0.f, 0.f, 0.f, 0.f};

    const float* ssb = ss + (size_t)chunk * NA * 2;

    // ---- GEMM: y[16 x 1024] = GBN(a_tile)[16 x 128] * W^T (operands swapped) ----
#pragma unroll
    for (int ks = 0; ks < 4; ++ks) {
        const int k0 = ks * 32 + g * 8;
        const float4* ap = (const float4*)(a + (size_t)(r0 + q) * NA + k0);
        float4 v0 = ap[0], v1 = ap[1];
        const float4* sp = (const float4*)(ssb + k0 * 2);   // interleaved (sc,sh)
        float4 s0 = sp[0], s1 = sp[1], s2 = sp[2], s3 = sp[3];
        bf16x8s af;
        af[0] = f2bf(v0.x * s0.x + s0.y);
        af[1] = f2bf(v0.y * s0.z + s0.w);
        af[2] = f2bf(v0.z * s1.x + s1.y);
        af[3] = f2bf(v0.w * s1.z + s1.w);
        af[4] = f2bf(v1.x * s2.x + s2.y);
        af[5] = f2bf(v1.y * s2.z + s2.w);
        af[6] = f2bf(v1.z * s3.x + s3.y);
        af[7] = f2bf(v1.w * s3.z + s3.w);

        const unsigned short* wb = Wb + (size_t)(wave * 256 + q) * NA + k0;
#pragma unroll
        for (int nf = 0; nf < 16; ++nf) {
            bf16x8s bf = *(const bf16x8s*)(wb + (size_t)nf * 16 * NA);
            // A-role = W fragment, B-role = a fragment:
            // C[i=d_local, j=b_local]: thread row = r0+q, cols = wave*256+nf*16+4g+[0,4)
            acc[nf] = __builtin_amdgcn_mfma_f32_16x16x32_bf16(bf, af, acc[nf], 0, 0, 0);
        }
    }

    // ---- multiply by prior: one float4 per fragment ----
    {
        const float* pb = prior + (size_t)(r0 + q) * D_OUT + wave * 256 + 4 * g;
#pragma unroll
        for (int nf = 0; nf < 16; ++nf) {
            float4 p = *(const float4*)(pb + nf * 16);
            acc[nf][0] *= p.x; acc[nf][1] *= p.y;
            acc[nf][2] *= p.z; acc[nf][3] *= p.w;
        }
    }

    // ---- transpose through LDS (bf16) so each 16-lane group owns one full row ----
    __shared__ unsigned short ls[16][1032];   // 1032 = 1024 + 8 pad (bank spread), 33 KB
#pragma unroll
    for (int nf = 0; nf < 16; ++nf) {
        u16x4 h;
        h[0] = (unsigned short)f2bf(acc[nf][0]);
        h[1] = (unsigned short)f2bf(acc[nf][1]);
        h[2] = (unsigned short)f2bf(acc[nf][2]);
        h[3] = (unsigned short)f2bf(acc[nf][3]);
        *(u16x4*)&ls[q][wave * 256 + nf * 16 + 4 * g] = h;
    }
    __syncthreads();

    const int lr = tid >> 4;          // local row 0..15
    const int l  = tid & 15;          // lane within row group
    float v[64];
#pragma unroll
    for (int j = 0; j < 8; ++j) {
        u16x8 hv = *(const u16x8*)&ls[lr][(l + 16 * j) * 8];
#pragma unroll
        for (int i = 0; i < 8; ++i) v[j * 8 + i] = bf2f(hv[i]);
    }

    // ---- Michelot fixed point: tau = (sum_{v>tau} v - 1)/count ----
    float tau = -3.0e38f, cprev = -1.f;
    for (int it = 0; it < 64; ++it) {
        float s = 0.f, c = 0.f;
#pragma unroll
        for (int e = 0; e < 64; ++e) {
            float x = v[e];
            bool m = x > tau;
            s += m ? x : 0.f;
            c += m ? 1.f : 0.f;
        }
#pragma unroll
        for (int m = 1; m < 16; m <<= 1) {
            s += __shfl_xor(s, m);
            c += __shfl_xor(c, m);
        }
        tau = (s - 1.f) / c;
        if (c == cprev) break;
        cprev = c;
    }

    // ---- output: relu(v + tau), vectorized float4 stores ----
    float* ob = out + (size_t)(r0 + lr) * D_OUT;
#pragma unroll
    for (int j = 0; j < 8; ++j) {
        float4 o0, o1;
        o0.x = fmaxf(v[j * 8 + 0] + tau, 0.f);
        o0.y = fmaxf(v[j * 8 + 1] + tau, 0.f);
        o0.z = fmaxf(v[j * 8 + 2] + tau, 0.f);
        o0.w = fmaxf(v[j * 8 + 3] + tau, 0.f);
        o1.x = fmaxf(v[j * 8 + 4] + tau, 0.f);
        o1.y = fmaxf(v[j * 8 + 5] + tau, 0.f);
        o1.z = fmaxf(v[j * 8 + 6] + tau, 0.f);
        o1.w = fmaxf(v[j * 8 + 7] + tau, 0.f);
        float* p = ob + (l + 16 * j) * 8;
        *(float4*)p = o0;
        *(float4*)(p + 4) = o1;
    }
}

extern "C" void kernel_launch(void* const* d_in, const int* in_sizes, int n_in,
                              void* d_out, int out_size, void* d_ws, size_t ws_size,
                              hipStream_t stream) {
    const float* a     = (const float*)d_in[0];
    const float* prior = (const float*)d_in[1];
    const float* gamma = (const float*)d_in[2];
    const float* beta  = (const float*)d_in[3];
    const float* W     = (const float*)d_in[4];
    float* out = (float*)d_out;

    float* ss = (float*)d_ws;                                   // 512 KB
    unsigned short* Wb = (unsigned short*)((char*)d_ws +
                         (size_t)NCHUNK * NA * 2 * sizeof(float)); // 256 KB

    gbn_stats_kernel<<<NCHUNK, VBS, 0, stream>>>(a, gamma, beta, ss);
    wcast_kernel<<<(D_OUT * NA + 255) / 256, 256, 0, stream>>>(W, Wb, D_OUT * NA);
    fused_kernel<<<B_ROWS / 16, 256, 0, stream>>>(a, prior, ss, Wb, out);
}

// Round 3
// 245.154 us; speedup vs baseline: 1.1491x; 1.1491x over previous
//
#include <hip/hip_runtime.h>
#include <hip/hip_bf16.h>

#define B_ROWS 65536
#define NA 128
#define D_OUT 1024
#define VBS 128
#define NCHUNK (B_ROWS / VBS)   // 512

typedef __attribute__((ext_vector_type(8))) short bf16x8s;
typedef __attribute__((ext_vector_type(4))) float f32x4;
typedef __attribute__((ext_vector_type(4))) unsigned short u16x4;

static __device__ __forceinline__ short f2bf(float f) {
    unsigned u = __builtin_bit_cast(unsigned, f);
    u = u + 0x7FFFu + ((u >> 16) & 1u);   // round-to-nearest-even to bf16
    return (short)(u >> 16);
}
static __device__ __forceinline__ float bf2f(unsigned short h) {
    unsigned u = ((unsigned)h) << 16;
    return __builtin_bit_cast(float, u);
}

// One block per virtual batch (chunk): 128 threads, one per feature.
__global__ void gbn_stats_kernel(const float* __restrict__ a,
                                 const float* __restrict__ gamma,
                                 const float* __restrict__ beta,
                                 float* __restrict__ ss) {
    int c = blockIdx.x;
    int j = threadIdx.x;            // feature 0..127
    const float* p = a + (size_t)c * (VBS * NA) + j;
    float s = 0.f, s2 = 0.f;
#pragma unroll 8
    for (int r = 0; r < VBS; ++r) {
        float v = p[r * NA];
        s += v; s2 += v * v;
    }
    float mean = s * (1.f / VBS);
    float var  = fmaxf(s2 * (1.f / VBS) - mean * mean, 0.f);   // biased var
    float sc = gamma[j] * rsqrtf(var + 1e-5f);
    float sh = beta[j] - mean * sc;
    float2* o = (float2*)ss + (c * NA + j);
    *o = make_float2(sc, sh);
}

__global__ void wcast_kernel(const float* __restrict__ W,
                             unsigned short* __restrict__ Wb, int n) {
    int i = blockIdx.x * blockDim.x + threadIdx.x;
    if (i < n) Wb[i] = (unsigned short)f2bf(W[i]);
}

// One block per 16 output rows. 256 threads = 4 waves; wave w owns cols [w*256, w*256+256)
// in the GEMM. Swapped-operand MFMA: thread (g,q) holds y[r0+q][w*256+nf*16+4g+r].
// Epilogue: *prior (float4), bf16 LDS transpose, then each wave processes its 4 rows
// SEQUENTIALLY: 16 f32 per lane (no spill), full-wave shfl_xor Michelot, coalesced out.
__global__ __launch_bounds__(256, 4) void fused_kernel(
    const float* __restrict__ a,
    const float* __restrict__ prior,
    const float* __restrict__ ss,
    const unsigned short* __restrict__ Wb,
    float* __restrict__ out) {

    const int tid  = threadIdx.x;
    const int wave = tid >> 6;        // 0..3  (N block of 256)
    const int lane = tid & 63;
    const int g    = lane >> 4;       // 0..3
    const int q    = lane & 15;       // output row within tile

    const int r0    = blockIdx.x * 16;
    const int chunk = r0 >> 7;

    f32x4 acc[16];
#pragma unroll
    for (int i = 0; i < 16; ++i) acc[i] = (f32x4){0.f, 0.f, 0.f, 0.f};

    const float* ssb = ss + (size_t)chunk * NA * 2;

    // ---- GEMM: y[16 x 1024] = GBN(a_tile)[16 x 128] * W^T (operands swapped) ----
#pragma unroll
    for (int ks = 0; ks < 4; ++ks) {
        const int k0 = ks * 32 + g * 8;
        const float4* ap = (const float4*)(a + (size_t)(r0 + q) * NA + k0);
        float4 v0 = ap[0], v1 = ap[1];
        const float4* sp = (const float4*)(ssb + k0 * 2);   // interleaved (sc,sh)
        float4 s0 = sp[0], s1 = sp[1], s2 = sp[2], s3 = sp[3];
        bf16x8s af;
        af[0] = f2bf(v0.x * s0.x + s0.y);
        af[1] = f2bf(v0.y * s0.z + s0.w);
        af[2] = f2bf(v0.z * s1.x + s1.y);
        af[3] = f2bf(v0.w * s1.z + s1.w);
        af[4] = f2bf(v1.x * s2.x + s2.y);
        af[5] = f2bf(v1.y * s2.z + s2.w);
        af[6] = f2bf(v1.z * s3.x + s3.y);
        af[7] = f2bf(v1.w * s3.z + s3.w);

        const unsigned short* wb = Wb + (size_t)(wave * 256 + q) * NA + k0;
#pragma unroll
        for (int nf = 0; nf < 16; ++nf) {
            bf16x8s bf = *(const bf16x8s*)(wb + (size_t)nf * 16 * NA);
            acc[nf] = __builtin_amdgcn_mfma_f32_16x16x32_bf16(bf, af, acc[nf], 0, 0, 0);
        }
    }

    // ---- multiply by prior: one float4 per fragment ----
    {
        const float* pb = prior + (size_t)(r0 + q) * D_OUT + wave * 256 + 4 * g;
#pragma unroll
        for (int nf = 0; nf < 16; ++nf) {
            float4 p = *(const float4*)(pb + nf * 16);
            acc[nf][0] *= p.x; acc[nf][1] *= p.y;
            acc[nf][2] *= p.z; acc[nf][3] *= p.w;
        }
    }

    // ---- transpose through LDS (bf16): each thread's 64 values belong to row q ----
    __shared__ unsigned short ls[16][1032];   // 1032 = 1024 + 8 pad, 33 KB
#pragma unroll
    for (int nf = 0; nf < 16; ++nf) {
        u16x4 h;
        h[0] = (unsigned short)f2bf(acc[nf][0]);
        h[1] = (unsigned short)f2bf(acc[nf][1]);
        h[2] = (unsigned short)f2bf(acc[nf][2]);
        h[3] = (unsigned short)f2bf(acc[nf][3]);
        *(u16x4*)&ls[q][wave * 256 + nf * 16 + 4 * g] = h;
    }
    __syncthreads();

    // ---- per-wave sequential row processing: 16 f32/lane, no barriers, no spill ----
#pragma unroll 1
    for (int rr = 0; rr < 4; ++rr) {
        const int row = wave * 4 + rr;
        float va[16];
#pragma unroll
        for (int j = 0; j < 4; ++j) {
            u16x4 hv = *(const u16x4*)&ls[row][j * 256 + lane * 4];
            va[j * 4 + 0] = bf2f(hv[0]);
            va[j * 4 + 1] = bf2f(hv[1]);
            va[j * 4 + 2] = bf2f(hv[2]);
            va[j * 4 + 3] = bf2f(hv[3]);
        }

        // iteration 1 hoisted: tau = (sum_all - 1)/1024
        float s = 0.f;
#pragma unroll
        for (int e = 0; e < 16; ++e) s += va[e];
#pragma unroll
        for (int m = 1; m < 64; m <<= 1) s += __shfl_xor(s, m);
        float tau = (s - 1.f) * (1.f / 1024.f);
        float cprev = 1024.f;

        for (int it = 0; it < 32; ++it) {
            s = 0.f; float c = 0.f;
#pragma unroll
            for (int e = 0; e < 16; ++e) {
                float x = va[e];
                bool mk = x > tau;
                s += mk ? x : 0.f;
                c += mk ? 1.f : 0.f;
            }
#pragma unroll
            for (int m = 1; m < 64; m <<= 1) {
                s += __shfl_xor(s, m);
                c += __shfl_xor(c, m);
            }
            tau = (s - 1.f) / c;
            if (c == cprev) break;
            cprev = c;
        }

        // ---- output: relu(v + tau), coalesced float4 stores ----
        float* ob = out + (size_t)(r0 + row) * D_OUT + lane * 4;
#pragma unroll
        for (int j = 0; j < 4; ++j) {
            float4 o;
            o.x = fmaxf(va[j * 4 + 0] + tau, 0.f);
            o.y = fmaxf(va[j * 4 + 1] + tau, 0.f);
            o.z = fmaxf(va[j * 4 + 2] + tau, 0.f);
            o.w = fmaxf(va[j * 4 + 3] + tau, 0.f);
            *(float4*)(ob + j * 256) = o;
        }
    }
}

extern "C" void kernel_launch(void* const* d_in, const int* in_sizes, int n_in,
                              void* d_out, int out_size, void* d_ws, size_t ws_size,
                              hipStream_t stream) {
    const float* a     = (const float*)d_in[0];
    const float* prior = (const float*)d_in[1];
    const float* gamma = (const float*)d_in[2];
    const float* beta  = (const float*)d_in[3];
    const float* W     = (const float*)d_in[4];
    float* out = (float*)d_out;

    float* ss = (float*)d_ws;                                   // 512 KB
    unsigned short* Wb = (unsigned short*)((char*)d_ws +
                         (size_t)NCHUNK * NA * 2 * sizeof(float)); // 256 KB

    gbn_stats_kernel<<<NCHUNK, VBS, 0, stream>>>(a, gamma, beta, ss);
    wcast_kernel<<<(D_OUT * NA + 255) / 256, 256, 0, stream>>>(W, Wb, D_OUT * NA);
    fused_kernel<<<B_ROWS / 16, 256, 0, stream>>>(a, prior, ss, Wb, out);
}